// Round 15
// baseline (284.409 us; speedup 1.0000x reference)
//
#include <hip/hip_runtime.h>

// ShrdMHAttention on MI355X (gfx950).
// k_prep -> merged proj GEMM (128^2, BK=64, 2-phase dbuf, counted vmcnt(8),
// gl_lds staging, RoPE epilogue) -> causal flash attention v8 (PER-WAVE private
// LDS staging, ZERO barriers, reg-prefetch, per-wave diagonal clipping) ->
// combine -> output GEMM (BM=64).
// Workspace: 0-30.5MB opart | 31MB mlbuf | 32MB obT | 40MB rq[->z] | 48MB rk |
// 56MB vst | 64MB tables.  Pre-proj: 0MB xb | 8..32MB merged W^T[6144][2048]

#define S_LEN   2048
#define D_MODEL 2048
#define NHEAD   16
#define DHEAD   128

using f32x4   = __attribute__((ext_vector_type(4))) float;
using f32x16  = __attribute__((ext_vector_type(16))) float;
using bf16x8  = __attribute__((ext_vector_type(8))) __bf16;

__device__ __forceinline__ unsigned short f2bf(float f) {
  unsigned int u = __builtin_bit_cast(unsigned int, f);
  u += 0x7fffu + ((u >> 16) & 1u);          // RNE
  return (unsigned short)(u >> 16);
}
__device__ __forceinline__ int chunks_of(int qt) { return (4 * qt + 13) / 10; } // ceil((4qt+4)/10)

// async global->LDS, 16B per lane. LDS dest is wave-uniform base + lane*16.
__device__ __forceinline__ void gl_lds16(const unsigned short* g, char* l) {
  __builtin_amdgcn_global_load_lds(
      (const __attribute__((address_space(1))) unsigned int*)g,
      (__attribute__((address_space(3))) unsigned int*)l, 16, 0, 0);
}

// ---------- merged prep: bf16-cvt(x) | rope tables | transpose q,k,v,o ----------
__global__ __launch_bounds__(256) void k_prep(
    const float* __restrict__ x, const float* __restrict__ q,
    const float* __restrict__ k, const float* __restrict__ v,
    const float* __restrict__ o, const float* __restrict__ theta_p,
    unsigned short* __restrict__ xb, unsigned short* __restrict__ wT,
    unsigned short* __restrict__ obT, float* __restrict__ sint,
    float* __restrict__ cost) {
  __shared__ float t[32][33];
  const int bid = blockIdx.x, tid = threadIdx.x;
  if (bid < 4096) {                          // x -> bf16
    int i = (bid * 256 + tid) * 4;
    float4 vv = *reinterpret_cast<const float4*>(x + i);
    ushort4 ov; ov.x = f2bf(vv.x); ov.y = f2bf(vv.y); ov.z = f2bf(vv.z); ov.w = f2bf(vv.w);
    *reinterpret_cast<ushort4*>(xb + i) = ov;
  } else if (bid < 4608) {                   // rope tables
    int i = (bid - 4096) * 256 + tid;
    int s = i >> 6, c = i & 63;
    float rate = theta_p[0] * (-(float)c / 64.0f);
    float sn, cs;
    sincosf((float)s * rate, &sn, &cs);
    sint[i] = sn; cost[i] = cs;
  } else {                                   // transpose+cvt: (B,R,C) -> (B,C,R)
    int ti = bid - 4608;
    int which = ti >> 12, i = ti & 4095;
    const float* ip; unsigned short* op; int C, b, rt, ct;
    const int R = 2048;
    if (which < 3) {
      C = 128; b = i >> 8; rt = (i >> 2) & 63; ct = i & 3;
      const float* src = which == 0 ? q : (which == 1 ? k : v);
      ip = src + (size_t)b * R * C;
      op = wT + (size_t)which * 4194304 + (size_t)b * R * C;
    } else {
      C = 2048; rt = i >> 6; ct = i & 63;
      ip = o; op = obT;
    }
    int tx = tid & 31, ty = tid >> 5;        // 32 x 8
    #pragma unroll
    for (int j = 0; j < 4; j++)
      t[ty + j * 8][tx] = ip[(size_t)(rt * 32 + ty + j * 8) * C + ct * 32 + tx];
    __syncthreads();
    #pragma unroll
    for (int j = 0; j < 4; j++)
      op[(size_t)(ct * 32 + ty + j * 8) * R + rt * 32 + tx] = f2bf(t[tx][ty + j * 8]);
  }
}

// ---------- merged projection GEMM: C(2048 x 6144) = xb @ W^T, RoPE epilogue ----------
// 768 blocks (XCD-swizzled); 4 waves x (32 rows x 128 cols); BK=64, 2-phase
// double-buffered gl_lds staging with counted vmcnt(8) — R8-verified structure.
__global__ __launch_bounds__(256) void k_proj2(
    const unsigned short* __restrict__ xb, const unsigned short* __restrict__ wT,
    const float* __restrict__ sint, const float* __restrict__ cost,
    unsigned short* __restrict__ rq, unsigned short* __restrict__ rk,
    unsigned short* __restrict__ vst) {
  __shared__ char lds[65536];               // buf0: A@0 B@16K | buf1: A@32K B@48K
  const int tid = threadIdx.x, l = tid & 63, w = tid >> 6;
  const int lr = l & 15, lk = l >> 4;
  const int orig = blockIdx.x;
  const int wg = (orig & 7) * 96 + (orig >> 3);   // XCD-contiguous remap (768%8==0)
  const int bx = wg & 15, by = wg >> 4;     // s-tile, n-tile
  const int s0 = bx * 128;
  const int h = by & 15, which = by >> 4;   // n-tile -> (head, q/k/v)
  const unsigned short* bbase = wT + (size_t)by * 128 * D_MODEL;

  f32x4 acc[2][8] = {};

  auto stage = [&](int t, int buf) {
    const int kt = t * 64;
    char* dst = lds + buf * 32768;
    #pragma unroll
    for (int j = 0; j < 4; j++) {
      int ci = (j * 4 + w) * 64 + l;        // 0..1023
      int r = ci >> 3, c8 = ci & 7;
      int csrc = (c8 ^ (r & 7)) * 8;
      gl_lds16(xb + (size_t)(s0 + r) * D_MODEL + kt + csrc, dst + ci * 16);
      gl_lds16(bbase + (size_t)r * D_MODEL + kt + csrc, dst + 16384 + ci * 16);
    }
  };

  stage(0, 0);
  int cur = 0;
  const int nT = D_MODEL / 64;              // 32
  for (int t = 0; t < nT; t++) {
    if (t + 1 < nT) {
      stage(t + 1, cur ^ 1);
      asm volatile("s_waitcnt vmcnt(8)" ::: "memory");   // buf[cur]'s 8 done
    } else {
      asm volatile("s_waitcnt vmcnt(0)" ::: "memory");
    }
    __builtin_amdgcn_s_barrier();           // all waves' buf[cur] resident
    const char* base = lds + cur * 32768;
    #pragma unroll
    for (int kk = 0; kk < 2; kk++) {
      const int kb = kk * 64 + lk * 16;
      bf16x8 a[2], b[8];
      #pragma unroll
      for (int mf = 0; mf < 2; mf++) {
        int rr = w * 32 + mf * 16 + lr;
        a[mf] = *reinterpret_cast<const bf16x8*>(base + rr * 128 + (kb ^ ((rr & 7) << 4)));
      }
      #pragma unroll
      for (int nf = 0; nf < 8; nf++) {
        int rn = nf * 16 + lr;
        b[nf] = *reinterpret_cast<const bf16x8*>(base + 16384 + rn * 128 + (kb ^ ((rn & 7) << 4)));
      }
      #pragma unroll
      for (int mf = 0; mf < 2; mf++)
        #pragma unroll
        for (int nf = 0; nf < 8; nf++)
          acc[mf][nf] = __builtin_amdgcn_mfma_f32_16x16x32_bf16(a[mf], b[nf], acc[mf][nf], 0, 0, 0);
    }
    asm volatile("s_waitcnt lgkmcnt(0)" ::: "memory");   // reads of buf[cur] done
    __builtin_amdgcn_s_barrier();           // before next iter overwrites buf[cur]
    cur ^= 1;
  }

  const float xscale = 0.022097086912079608f;             // 1/sqrt(2048)
  const float qsc = xscale * 0.08838834764831845f;        // * 1/sqrt(128) folded
  if (which < 2) {
    const float sc_out = (which == 0) ? qsc : xscale;
    unsigned short* dst = (which == 0 ? rq : rk) + (size_t)h * S_LEN * DHEAD;
    #pragma unroll
    for (int mf = 0; mf < 2; mf++) {
      #pragma unroll
      for (int nf = 0; nf < 4; nf++) {
        int c1 = nf * 16 + lr;
        #pragma unroll
        for (int rg = 0; rg < 4; rg++) {
          int srow = s0 + w * 32 + mf * 16 + lk * 4 + rg;
          float sn = sint[srow * 64 + c1], cs = cost[srow * 64 + c1];
          float x1 = acc[mf][nf][rg] * sc_out;
          float x2 = acc[mf][nf + 4][rg] * sc_out;
          dst[(size_t)srow * DHEAD + c1]      = f2bf(cs * x1 - sn * x2);
          dst[(size_t)srow * DHEAD + c1 + 64] = f2bf(sn * x1 + cs * x2);
        }
      }
    }
  } else {                                      // v: store transposed vst[h][c][s]
    unsigned short* dst = vst + (size_t)h * DHEAD * S_LEN;
    #pragma unroll
    for (int mf = 0; mf < 2; mf++) {
      int rbase = s0 + w * 32 + mf * 16 + lk * 4;
      #pragma unroll
      for (int nf = 0; nf < 8; nf++) {
        int c = nf * 16 + lr;
        ushort4 ov;
        ov.x = f2bf(acc[mf][nf][0] * xscale); ov.y = f2bf(acc[mf][nf][1] * xscale);
        ov.z = f2bf(acc[mf][nf][2] * xscale); ov.w = f2bf(acc[mf][nf][3] * xscale);
        *reinterpret_cast<ushort4*>(dst + (size_t)c * S_LEN + rbase) = ov;
      }
    }
  }
}

// ---------- causal flash attention v8: PER-WAVE private LDS, zero barriers ----------
// 976 blocks; wave w owns region lds[w*18944 .. +18944): K rows @272B | Vt @80B.
// Each wave stages its own tiles (L2-resident K/V, x4 redundancy ~ L2 BW), clips
// its loop at its own diagonal, reg-prefetches t+1 under compute of t. No
// __syncthreads, no inline-asm waits — compiler dep-tracking + in-order DS pipe.
__global__ __launch_bounds__(256, 2) void k_attn8(
    const unsigned short* __restrict__ rq, const unsigned short* __restrict__ rk,
    const unsigned short* __restrict__ vst,
    unsigned short* __restrict__ opart, float2* __restrict__ mlbuf) {
  __shared__ char lds[75776];               // 4 x 18944 per-wave regions
  const int tid = threadIdx.x, l = tid & 63, w = tid >> 6;
  const int hi = l >> 5, qcol = l & 31;
  const int b = blockIdx.x;
  const int h = b & 15;                     // head h -> XCD h&7 (K/V L2 locality)
  int u = b >> 4, qt = 0;
  while (u >= chunks_of(qt)) { u -= chunks_of(qt); qt++; }
  const int ntile = 4 * qt + 4;
  const int tbeg = u * 10;
  const int tend = (tbeg + 10 < ntile) ? tbeg + 10 : ntile;
  const int s0w = qt * 128 + w * 32;
  const int dtile = s0w >> 5;               // this wave's diagonal tile = 4qt+w
  const int wend = (tend < dtile + 1) ? tend : dtile + 1;  // clip masked-out tiles

  char* kb = lds + w * 18944;               // private K region (32 rows @272B)
  char* vb = kb + 8704;                     // private Vt region (128 rows @80B)

  const unsigned short* rk_h  = rk  + (size_t)h * S_LEN * DHEAD;
  const unsigned short* vst_h = vst + (size_t)h * DHEAD * S_LEN;

  const unsigned short* qrow_p = rq + ((size_t)h * S_LEN + s0w + qcol) * DHEAD + hi * 8;
  bf16x8 qb[8];
  #pragma unroll
  for (int kk = 0; kk < 8; kk++)
    qb[kk] = *reinterpret_cast<const bf16x8*>(qrow_p + kk * 16);

  f32x16 O[4] = {};
  float mrow = -3.0e38f, lrow = 0.0f;

  uint4 kreg[8], vreg[8];
  auto ld_regs = [&](int t) {               // wave-local: issue tile t's loads
    const int t0 = t * 32;
    #pragma unroll
    for (int j = 0; j < 8; j++) {
      int ci = j * 64 + l;                  // 0..511
      kreg[j] = *reinterpret_cast<const uint4*>(
          rk_h + (size_t)(t0 + (ci >> 4)) * DHEAD + (ci & 15) * 8);
      vreg[j] = *reinterpret_cast<const uint4*>(
          vst_h + (size_t)(ci >> 2) * S_LEN + t0 + (ci & 3) * 8);
    }
  };
  auto wr_lds = [&]() {                     // wave-local: write regs to region
    #pragma unroll
    for (int j = 0; j < 8; j++) {
      int ci = j * 64 + l;
      *reinterpret_cast<uint4*>(kb + (ci >> 4) * 272 + (ci & 15) * 16) = kreg[j];
      *reinterpret_cast<uint4*>(vb + (ci >> 2) * 80 + (ci & 3) * 16) = vreg[j];
    }
  };

  if (tbeg < wend) {
    ld_regs(tbeg);
    wr_lds();
    if (tbeg + 1 < wend) ld_regs(tbeg + 1);
  }

  for (int t = tbeg; t < wend; t++) {
    // --- QK^T (R2-verified math; reads this wave's region) ---
    f32x16 sc = {};
    __builtin_amdgcn_s_setprio(1);
    #pragma unroll
    for (int kk = 0; kk < 8; kk++) {
      bf16x8 ka = *reinterpret_cast<const bf16x8*>(kb + qcol * 272 + kk * 32 + hi * 16);
      sc = __builtin_amdgcn_mfma_f32_32x32x16_bf16(ka, qb[kk], sc, 0, 0, 0);
    }
    __builtin_amdgcn_s_setprio(0);
    float p[16];
    #pragma unroll
    for (int r = 0; r < 16; r++) p[r] = sc[r];
    if (t == dtile) {                       // diagonal tile: causal mask
      #pragma unroll
      for (int r = 0; r < 16; r++)
        if (((r & 3) + 8 * (r >> 2) + 4 * hi) > qcol) p[r] = -1.0e9f;
    }
    float mx[8];
    #pragma unroll
    for (int i = 0; i < 8; i++) mx[i] = fmaxf(p[2 * i], p[2 * i + 1]);
    #pragma unroll
    for (int i = 0; i < 4; i++) mx[i] = fmaxf(mx[i], mx[i + 4]);
    mx[0] = fmaxf(mx[0], mx[2]); mx[1] = fmaxf(mx[1], mx[3]);
    float pmax = fmaxf(mx[0], mx[1]);
    pmax = fmaxf(pmax, __shfl_xor(pmax, 32, 64));
    if (__any(pmax > mrow + 8.0f)) {
      float mn = fmaxf(mrow, pmax);
      float sf = __expf(mrow - mn);
      lrow *= sf; mrow = mn;
      #pragma unroll
      for (int vc = 0; vc < 4; vc++)
        #pragma unroll
        for (int r = 0; r < 16; r++) O[vc][r] *= sf;
    }
    #pragma unroll
    for (int r = 0; r < 16; r++) p[r] = __expf(p[r] - mrow);
    float sm[8];
    #pragma unroll
    for (int i = 0; i < 8; i++) sm[i] = p[2 * i] + p[2 * i + 1];
    #pragma unroll
    for (int i = 0; i < 4; i++) sm[i] += sm[i + 4];
    float psum = (sm[0] + sm[1]) + (sm[2] + sm[3]);
    psum += __shfl_xor(psum, 32, 64);
    lrow += psum;
    unsigned int pk[2][4], sw[2][4];
    #pragma unroll
    for (int c = 0; c < 2; c++)
      #pragma unroll
      for (int k = 0; k < 4; k++) {
        unsigned int r_;
        asm("v_cvt_pk_bf16_f32 %0, %1, %2" : "=v"(r_)
            : "v"(p[8 * c + 2 * k]), "v"(p[8 * c + 2 * k + 1]));
        pk[c][k] = r_;
        sw[c][k] = (unsigned int)__shfl_xor((int)r_, 32, 64);
      }
    bf16x8 pb[2];
    #pragma unroll
    for (int c = 0; c < 2; c++) {
      union { unsigned int u4[4]; bf16x8 v; } bw;
      bw.u4[0] = hi ? sw[c][2] : pk[c][0];
      bw.u4[1] = hi ? sw[c][3] : pk[c][1];
      bw.u4[2] = hi ? pk[c][2] : sw[c][0];
      bw.u4[3] = hi ? pk[c][3] : sw[c][1];
      pb[c] = bw.v;
    }
    __builtin_amdgcn_s_setprio(1);
    #pragma unroll
    for (int vc = 0; vc < 4; vc++) {
      const char* vrow = vb + (vc * 32 + qcol) * 80 + hi * 16;
      bf16x8 va0 = *reinterpret_cast<const bf16x8*>(vrow);
      bf16x8 va1 = *reinterpret_cast<const bf16x8*>(vrow + 32);
      O[vc] = __builtin_amdgcn_mfma_f32_32x32x16_bf16(va0, pb[0], O[vc], 0, 0, 0);
      O[vc] = __builtin_amdgcn_mfma_f32_32x32x16_bf16(va1, pb[1], O[vc], 0, 0, 0);
    }
    __builtin_amdgcn_s_setprio(0);
    // stage tile t+1 into region (DS in-order: after this tile's reads), then
    // prefetch t+2 into regs. No barriers — region is wave-private.
    if (t + 1 < wend) {
      wr_lds();
      if (t + 2 < wend) ld_regs(t + 2);
    }
  }

  // --- per-wave O-bounce through own K region (no sync needed) ---
  float inv = lrow > 0.0f ? 1.0f / lrow : 0.0f;
  #pragma unroll
  for (int vc = 0; vc < 4; vc++)
    #pragma unroll
    for (int g = 0; g < 4; g++) {
      int v0 = vc * 32 + 8 * g + 4 * hi;
      ushort4 ov;
      ov.x = f2bf(O[vc][4 * g + 0] * inv); ov.y = f2bf(O[vc][4 * g + 1] * inv);
      ov.z = f2bf(O[vc][4 * g + 2] * inv); ov.w = f2bf(O[vc][4 * g + 3] * inv);
      *reinterpret_cast<ushort4*>(kb + qcol * 272 + v0 * 2) = ov;
    }
  #pragma unroll
  for (int j = 0; j < 8; j++) {             // wave covers 1KB contiguous per instr
    int lr8 = j * 4 + (l >> 4);             // local row 0..31
    uint4 vv = *reinterpret_cast<const uint4*>(kb + lr8 * 272 + (l & 15) * 16);
    *reinterpret_cast<uint4*>(opart + ((size_t)b * 128 + w * 32 + lr8) * DHEAD + (l & 15) * 8) = vv;
  }
  if (l < 32)
    mlbuf[(size_t)b * 128 + w * 32 + l] = make_float2(mrow, lrow);
}

// ---------- combine up to 7 chunk partials per (h, q-row) ----------
__global__ void k_comb2(const unsigned short* __restrict__ opart,
                        const float2* __restrict__ mlbuf,
                        unsigned short* __restrict__ z) {
  int g = blockIdx.x * 256 + threadIdx.x;     // 16h * 2048q * 16vg
  int vg = g & 15, q = (g >> 4) & 2047, h = g >> 15;
  int qt = q >> 7, r = q & 127;
  int base = 0;
  for (int j = 0; j < qt; j++) base += chunks_of(j);
  const int nc = chunks_of(qt);               // 1..7
  float m = -3.0e38f;
  float2 ml[7];
  #pragma unroll
  for (int cc = 0; cc < 7; cc++)
    if (cc < nc) {
      ml[cc] = mlbuf[(size_t)((base + cc) * 16 + h) * 128 + r];
      m = fmaxf(m, ml[cc].x);
    }
  float wts[7], wsum = 0.0f;
  #pragma unroll
  for (int cc = 0; cc < 7; cc++)
    if (cc < nc) {
      float wv = ml[cc].y > 0.0f ? ml[cc].y * __expf(ml[cc].x - m) : 0.0f;
      wts[cc] = wv; wsum += wv;
    }
  float wi = 1.0f / wsum;
  float acc[8] = {};
  #pragma unroll
  for (int cc = 0; cc < 7; cc++)
    if (cc < nc && wts[cc] > 0.0f) {
      float wv = wts[cc] * wi;
      bf16x8 v = *reinterpret_cast<const bf16x8*>(
          opart + ((size_t)((base + cc) * 16 + h) * 128 + r) * DHEAD + vg * 8);
      #pragma unroll
      for (int j = 0; j < 8; j++) acc[j] += wv * (float)v[j];
    }
  unsigned short* zp = z + (size_t)q * D_MODEL + h * DHEAD + vg * 8;
  ushort4 lo, hi4;
  lo.x = f2bf(acc[0]); lo.y = f2bf(acc[1]); lo.z = f2bf(acc[2]); lo.w = f2bf(acc[3]);
  hi4.x = f2bf(acc[4]); hi4.y = f2bf(acc[5]); hi4.z = f2bf(acc[6]); hi4.w = f2bf(acc[7]);
  *reinterpret_cast<ushort4*>(zp) = lo;
  *reinterpret_cast<ushort4*>(zp + 4) = hi4;
}

// ---------- output GEMM: out(S,D) = z @ obT^T; BM=64 BN=128 BK=64, grid 512 ----------
__global__ __launch_bounds__(256) void k_out2(
    const unsigned short* __restrict__ zb, const unsigned short* __restrict__ obT,
    float* __restrict__ out) {
  __shared__ char lds[49152];               // buf p @ p*24576: A[64][128B] | B[128][128B] @+8K
  const int tid = threadIdx.x, l = tid & 63, w = tid >> 6;
  const int lr = l & 15, lk = l >> 4;
  const int orig = blockIdx.x;
  const int wg = (orig & 7) * 64 + (orig >> 3);   // 512%8==0, bijective
  const int bx = wg & 31, by = wg >> 5;     // s-tile(64), n-tile(128)
  const int s0 = bx * 64, n0 = by * 128;
  const int wm = w >> 1, wn = w & 1;        // wave = 32 rows x 64 cols
  f32x4 acc[2][4] = {};

  auto stage = [&](int t, int buf) {        // 6 gl_lds/thread (2 A + 4 B)
    const int kt = t * 64;
    char* dst = lds + buf * 24576;
    #pragma unroll
    for (int j = 0; j < 2; j++) {           // A: 64 rows x 8 chunks = 512
      int ci = tid + j * 256;
      int r = ci >> 3, c8 = ci & 7;
      int csrc = (c8 ^ (r & 7)) * 8;
      gl_lds16(zb + (size_t)(s0 + r) * D_MODEL + kt + csrc, dst + ci * 16);
    }
    #pragma unroll
    for (int j = 0; j < 4; j++) {           // B: 128 rows x 8 chunks = 1024
      int ci = tid + j * 256;
      int r = ci >> 3, c8 = ci & 7;
      int csrc = (c8 ^ (r & 7)) * 8;
      gl_lds16(obT + (size_t)(n0 + r) * D_MODEL + kt + csrc, dst + 8192 + ci * 16);
    }
  };

  stage(0, 0);
  int cur = 0;
  const int nT = D_MODEL / 64;
  for (int t = 0; t < nT; t++) {
    if (t + 1 < nT) {
      stage(t + 1, cur ^ 1);
      asm volatile("s_waitcnt vmcnt(6)" ::: "memory");
    } else {
      asm volatile("s_waitcnt vmcnt(0)" ::: "memory");
    }
    __builtin_amdgcn_s_barrier();
    const char* base = lds + cur * 24576;
    #pragma unroll
    for (int kk = 0; kk < 2; kk++) {
      const int kb = kk * 64 + lk * 16;
      bf16x8 a[2], b[4];
      #pragma unroll
      for (int mf = 0; mf < 2; mf++) {
        int rr = wm * 32 + mf * 16 + lr;
        a[mf] = *reinterpret_cast<const bf16x8*>(base + rr * 128 + (kb ^ ((rr & 7) << 4)));
      }
      #pragma unroll
      for (int nf = 0; nf < 4; nf++) {
        int rn = wn * 64 + nf * 16 + lr;
        b[nf] = *reinterpret_cast<const bf16x8*>(base + 8192 + rn * 128 + (kb ^ ((rn & 7) << 4)));
      }
      #pragma unroll
      for (int mf = 0; mf < 2; mf++)
        #pragma unroll
        for (int nf = 0; nf < 4; nf++)
          acc[mf][nf] = __builtin_amdgcn_mfma_f32_16x16x32_bf16(a[mf], b[nf], acc[mf][nf], 0, 0, 0);
    }
    asm volatile("s_waitcnt lgkmcnt(0)" ::: "memory");
    __builtin_amdgcn_s_barrier();
    cur ^= 1;
  }
  const float osc = 0.022097086912079608f;      // 1/sqrt(2048)
  #pragma unroll
  for (int mf = 0; mf < 2; mf++)
    #pragma unroll
    for (int nf = 0; nf < 4; nf++)
      #pragma unroll
      for (int rg = 0; rg < 4; rg++)
        out[(size_t)(s0 + wm * 32 + mf * 16 + lk * 4 + rg) * D_MODEL + n0 + wn * 64 + nf * 16 + lr]
            = acc[mf][nf][rg] * osc;
}

extern "C" void kernel_launch(void* const* d_in, const int* in_sizes, int n_in,
                              void* d_out, int out_size, void* d_ws, size_t ws_size,
                              hipStream_t stream) {
  const float* x = (const float*)d_in[0];
  const float* q = (const float*)d_in[1];
  const float* k = (const float*)d_in[2];
  const float* v = (const float*)d_in[3];
  const float* o = (const float*)d_in[4];
  const float* theta = (const float*)d_in[5];
  float* out = (float*)d_out;

  char* ws = (char*)d_ws;
  const size_t MB = 1u << 20;
  unsigned short* xb  = (unsigned short*)(ws + 0 * MB);
  unsigned short* qbT = (unsigned short*)(ws + 8 * MB);   // merged W^T[6144][2048] start
  unsigned short* obT = (unsigned short*)(ws + 32 * MB);
  unsigned short* rq  = (unsigned short*)(ws + 40 * MB);
  unsigned short* rk  = (unsigned short*)(ws + 48 * MB);
  unsigned short* vst = (unsigned short*)(ws + 56 * MB);
  float* sint = (float*)(ws + 64 * MB);
  float* cost = (float*)(ws + 64 * MB + 512 * 1024);
  unsigned short* opart = (unsigned short*)(ws + 0 * MB);   // 976*128*128*2B = 30.5MB
  float2* mlbuf         = (float2*)(ws + 31 * MB);          // 976*128*8B ~ 1MB
  unsigned short* zb    = (unsigned short*)(ws + 40 * MB);  // reuse rq (dead after attn)

  k_prep<<<dim3(20992), dim3(256), 0, stream>>>(x, q, k, v, o, theta, xb, qbT, obT, sint, cost);
  k_proj2<<<dim3(768), dim3(256), 0, stream>>>(xb, qbT, sint, cost, rq, rk, vst);
  k_attn8<<<dim3(976), dim3(256), 0, stream>>>(rq, rk, vst, opart, mlbuf);
  k_comb2<<<dim3(2048), dim3(256), 0, stream>>>(opart, mlbuf, zb);
  k_out2<<<dim3(512), dim3(256), 0, stream>>>(zb, obT, out);
}

// Round 16
// 172.367 us; speedup vs baseline: 1.6500x; 1.6500x over previous
//
#include <hip/hip_runtime.h>

// ShrdMHAttention on MI355X (gfx950).  FINAL (= R11 champion, 172.9us).
// k_prep -> merged proj GEMM (128^2 tile, BK=64, 2-phase dbuf, counted vmcnt(8),
// gl_lds staging, RoPE epilogue) -> causal flash attention (dbuf padded-LDS K/V,
// one barrier/tile, swapped QK^T, in-register softmax, uniform kv-chunks,
// LDS-bounced O-write) -> combine -> output GEMM (BM=64).
// Workspace: 0-30.5MB opart | 31MB mlbuf | 32MB obT | 40MB rq[->z] | 48MB rk |
// 56MB vst | 64MB tables.  Pre-proj: 0MB xb | 8..32MB merged W^T[6144][2048]

#define S_LEN   2048
#define D_MODEL 2048
#define NHEAD   16
#define DHEAD   128

using f32x4   = __attribute__((ext_vector_type(4))) float;
using f32x16  = __attribute__((ext_vector_type(16))) float;
using bf16x8  = __attribute__((ext_vector_type(8))) __bf16;

__device__ __forceinline__ unsigned short f2bf(float f) {
  unsigned int u = __builtin_bit_cast(unsigned int, f);
  u += 0x7fffu + ((u >> 16) & 1u);          // RNE
  return (unsigned short)(u >> 16);
}
__device__ __forceinline__ int chunks_of(int qt) { return (4 * qt + 13) / 10; } // ceil((4qt+4)/10)

// async global->LDS, 16B per lane. LDS dest is wave-uniform base + lane*16.
__device__ __forceinline__ void gl_lds16(const unsigned short* g, char* l) {
  __builtin_amdgcn_global_load_lds(
      (const __attribute__((address_space(1))) unsigned int*)g,
      (__attribute__((address_space(3))) unsigned int*)l, 16, 0, 0);
}

// ---------- merged prep: bf16-cvt(x) | rope tables | transpose q,k,v,o ----------
__global__ __launch_bounds__(256) void k_prep(
    const float* __restrict__ x, const float* __restrict__ q,
    const float* __restrict__ k, const float* __restrict__ v,
    const float* __restrict__ o, const float* __restrict__ theta_p,
    unsigned short* __restrict__ xb, unsigned short* __restrict__ wT,
    unsigned short* __restrict__ obT, float* __restrict__ sint,
    float* __restrict__ cost) {
  __shared__ float t[32][33];
  const int bid = blockIdx.x, tid = threadIdx.x;
  if (bid < 4096) {                          // x -> bf16
    int i = (bid * 256 + tid) * 4;
    float4 vv = *reinterpret_cast<const float4*>(x + i);
    ushort4 ov; ov.x = f2bf(vv.x); ov.y = f2bf(vv.y); ov.z = f2bf(vv.z); ov.w = f2bf(vv.w);
    *reinterpret_cast<ushort4*>(xb + i) = ov;
  } else if (bid < 4608) {                   // rope tables
    int i = (bid - 4096) * 256 + tid;
    int s = i >> 6, c = i & 63;
    float rate = theta_p[0] * (-(float)c / 64.0f);
    float sn, cs;
    sincosf((float)s * rate, &sn, &cs);
    sint[i] = sn; cost[i] = cs;
  } else {                                   // transpose+cvt: (B,R,C) -> (B,C,R)
    int ti = bid - 4608;
    int which = ti >> 12, i = ti & 4095;
    const float* ip; unsigned short* op; int C, b, rt, ct;
    const int R = 2048;
    if (which < 3) {
      C = 128; b = i >> 8; rt = (i >> 2) & 63; ct = i & 3;
      const float* src = which == 0 ? q : (which == 1 ? k : v);
      ip = src + (size_t)b * R * C;
      op = wT + (size_t)which * 4194304 + (size_t)b * R * C;
    } else {
      C = 2048; rt = i >> 6; ct = i & 63;
      ip = o; op = obT;
    }
    int tx = tid & 31, ty = tid >> 5;        // 32 x 8
    #pragma unroll
    for (int j = 0; j < 4; j++)
      t[ty + j * 8][tx] = ip[(size_t)(rt * 32 + ty + j * 8) * C + ct * 32 + tx];
    __syncthreads();
    #pragma unroll
    for (int j = 0; j < 4; j++)
      op[(size_t)(ct * 32 + ty + j * 8) * R + rt * 32 + tx] = f2bf(t[tx][ty + j * 8]);
  }
}

// ---------- merged projection GEMM: C(2048 x 6144) = xb @ W^T, RoPE epilogue ----------
// 768 blocks (XCD-swizzled); 4 waves x (32 rows x 128 cols); BK=64, 2-phase
// double-buffered gl_lds staging with counted vmcnt(8) — R8-verified structure.
__global__ __launch_bounds__(256) void k_proj2(
    const unsigned short* __restrict__ xb, const unsigned short* __restrict__ wT,
    const float* __restrict__ sint, const float* __restrict__ cost,
    unsigned short* __restrict__ rq, unsigned short* __restrict__ rk,
    unsigned short* __restrict__ vst) {
  __shared__ char lds[65536];               // buf0: A@0 B@16K | buf1: A@32K B@48K
  const int tid = threadIdx.x, l = tid & 63, w = tid >> 6;
  const int lr = l & 15, lk = l >> 4;
  const int orig = blockIdx.x;
  const int wg = (orig & 7) * 96 + (orig >> 3);   // XCD-contiguous remap (768%8==0)
  const int bx = wg & 15, by = wg >> 4;     // s-tile, n-tile
  const int s0 = bx * 128;
  const int h = by & 15, which = by >> 4;   // n-tile -> (head, q/k/v)
  const unsigned short* bbase = wT + (size_t)by * 128 * D_MODEL;

  f32x4 acc[2][8] = {};

  auto stage = [&](int t, int buf) {
    const int kt = t * 64;
    char* dst = lds + buf * 32768;
    #pragma unroll
    for (int j = 0; j < 4; j++) {
      int ci = (j * 4 + w) * 64 + l;        // 0..1023
      int r = ci >> 3, c8 = ci & 7;
      int csrc = (c8 ^ (r & 7)) * 8;
      gl_lds16(xb + (size_t)(s0 + r) * D_MODEL + kt + csrc, dst + ci * 16);
      gl_lds16(bbase + (size_t)r * D_MODEL + kt + csrc, dst + 16384 + ci * 16);
    }
  };

  stage(0, 0);
  int cur = 0;
  const int nT = D_MODEL / 64;              // 32
  for (int t = 0; t < nT; t++) {
    if (t + 1 < nT) {
      stage(t + 1, cur ^ 1);
      asm volatile("s_waitcnt vmcnt(8)" ::: "memory");   // buf[cur]'s 8 done
    } else {
      asm volatile("s_waitcnt vmcnt(0)" ::: "memory");
    }
    __builtin_amdgcn_s_barrier();           // all waves' buf[cur] resident
    const char* base = lds + cur * 32768;
    #pragma unroll
    for (int kk = 0; kk < 2; kk++) {
      const int kb = kk * 64 + lk * 16;
      bf16x8 a[2], b[8];
      #pragma unroll
      for (int mf = 0; mf < 2; mf++) {
        int rr = w * 32 + mf * 16 + lr;
        a[mf] = *reinterpret_cast<const bf16x8*>(base + rr * 128 + (kb ^ ((rr & 7) << 4)));
      }
      #pragma unroll
      for (int nf = 0; nf < 8; nf++) {
        int rn = nf * 16 + lr;
        b[nf] = *reinterpret_cast<const bf16x8*>(base + 16384 + rn * 128 + (kb ^ ((rn & 7) << 4)));
      }
      #pragma unroll
      for (int mf = 0; mf < 2; mf++)
        #pragma unroll
        for (int nf = 0; nf < 8; nf++)
          acc[mf][nf] = __builtin_amdgcn_mfma_f32_16x16x32_bf16(a[mf], b[nf], acc[mf][nf], 0, 0, 0);
    }
    asm volatile("s_waitcnt lgkmcnt(0)" ::: "memory");   // reads of buf[cur] done
    __builtin_amdgcn_s_barrier();           // before next iter overwrites buf[cur]
    cur ^= 1;
  }

  const float xscale = 0.022097086912079608f;             // 1/sqrt(2048)
  const float qsc = xscale * 0.08838834764831845f;        // * 1/sqrt(128) folded
  if (which < 2) {
    const float sc_out = (which == 0) ? qsc : xscale;
    unsigned short* dst = (which == 0 ? rq : rk) + (size_t)h * S_LEN * DHEAD;
    #pragma unroll
    for (int mf = 0; mf < 2; mf++) {
      #pragma unroll
      for (int nf = 0; nf < 4; nf++) {
        int c1 = nf * 16 + lr;
        #pragma unroll
        for (int rg = 0; rg < 4; rg++) {
          int srow = s0 + w * 32 + mf * 16 + lk * 4 + rg;
          float sn = sint[srow * 64 + c1], cs = cost[srow * 64 + c1];
          float x1 = acc[mf][nf][rg] * sc_out;
          float x2 = acc[mf][nf + 4][rg] * sc_out;
          dst[(size_t)srow * DHEAD + c1]      = f2bf(cs * x1 - sn * x2);
          dst[(size_t)srow * DHEAD + c1 + 64] = f2bf(sn * x1 + cs * x2);
        }
      }
    }
  } else {                                      // v: store transposed vst[h][c][s]
    unsigned short* dst = vst + (size_t)h * DHEAD * S_LEN;
    #pragma unroll
    for (int mf = 0; mf < 2; mf++) {
      int rbase = s0 + w * 32 + mf * 16 + lk * 4;
      #pragma unroll
      for (int nf = 0; nf < 8; nf++) {
        int c = nf * 16 + lr;
        ushort4 ov;
        ov.x = f2bf(acc[mf][nf][0] * xscale); ov.y = f2bf(acc[mf][nf][1] * xscale);
        ov.z = f2bf(acc[mf][nf][2] * xscale); ov.w = f2bf(acc[mf][nf][3] * xscale);
        *reinterpret_cast<ushort4*>(dst + (size_t)c * S_LEN + rbase) = ov;
      }
    }
  }
}

// ---------- causal flash attention v6: single-barrier dbuf, bounced O-write ----------
__global__ __launch_bounds__(256, 2) void k_attn6(
    const unsigned short* __restrict__ rq, const unsigned short* __restrict__ rk,
    const unsigned short* __restrict__ vst,
    unsigned short* __restrict__ opart, float2* __restrict__ mlbuf) {
  __shared__ uint4 ldsbuf[2368];            // 37888 B
  char* lds = (char*)ldsbuf;
  const int tid = threadIdx.x, l = tid & 63, w = tid >> 6;
  const int hi = l >> 5, qcol = l & 31;
  const int b = blockIdx.x;
  const int h = b & 15;                     // head h -> XCD h&7 (K/V L2 locality)
  int u = b >> 4, qt = 0;
  while (u >= chunks_of(qt)) { u -= chunks_of(qt); qt++; }
  const int ntile = 4 * qt + 4;
  const int tbeg = u * 10;
  const int tend = (tbeg + 10 < ntile) ? tbeg + 10 : ntile;
  const int s0w = qt * 128 + w * 32;
  const int wlast = s0w + 31;
  const int dtile = s0w >> 5;               // diagonal tile index

  const unsigned short* rk_h  = rk  + (size_t)h * S_LEN * DHEAD;
  const unsigned short* vst_h = vst + (size_t)h * DHEAD * S_LEN;

  const unsigned short* qrow_p = rq + ((size_t)h * S_LEN + s0w + qcol) * DHEAD + hi * 8;
  bf16x8 qb[8];
  #pragma unroll
  for (int kk = 0; kk < 8; kk++)
    qb[kk] = *reinterpret_cast<const bf16x8*>(qrow_p + kk * 16);

  f32x16 O[4] = {};
  float mrow = -3.0e38f, lrow = 0.0f;

  uint4 kreg[2], vreg[2];
  auto ld_regs = [&](int t) {               // issue tile t's global loads
    const int t0 = t * 32;
    #pragma unroll
    for (int j = 0; j < 2; j++) {
      int ci = tid + j * 256;
      kreg[j] = *reinterpret_cast<const uint4*>(rk_h + (size_t)(t0 + (ci >> 4)) * DHEAD + (ci & 15) * 8);
      vreg[j] = *reinterpret_cast<const uint4*>(vst_h + (size_t)(ci >> 2) * S_LEN + t0 + (ci & 3) * 8);
    }
  };
  auto wr_lds = [&](int p) {                // write staged regs into buffer p
    char* dst = lds + p * 18944;
    #pragma unroll
    for (int j = 0; j < 2; j++) {
      int ci = tid + j * 256;
      *reinterpret_cast<uint4*>(dst + (ci >> 4) * 272 + (ci & 15) * 16) = kreg[j];
      *reinterpret_cast<uint4*>(dst + 8704 + (ci >> 2) * 80 + (ci & 3) * 16) = vreg[j];
    }
  };

  ld_regs(tbeg);
  wr_lds(0);
  if (tbeg + 1 < tend) ld_regs(tbeg + 1);
  asm volatile("s_waitcnt lgkmcnt(0)" ::: "memory");
  __builtin_amdgcn_s_barrier();

  int cur = 0;
  for (int t = tbeg; t < tend; t++) {
    const char* kb = lds + cur * 18944;
    const char* vb = kb + 8704;
    const int tt0 = t * 32;
    if (tt0 <= wlast) {
      f32x16 sc = {};
      #pragma unroll
      for (int kk = 0; kk < 8; kk++) {
        bf16x8 ka = *reinterpret_cast<const bf16x8*>(kb + qcol * 272 + kk * 32 + hi * 16);
        sc = __builtin_amdgcn_mfma_f32_32x32x16_bf16(ka, qb[kk], sc, 0, 0, 0);
      }
      float p[16];
      #pragma unroll
      for (int r = 0; r < 16; r++) p[r] = sc[r];
      if (t == dtile) {                     // diagonal tile: causal mask
        #pragma unroll
        for (int r = 0; r < 16; r++)
          if (((r & 3) + 8 * (r >> 2) + 4 * hi) > qcol) p[r] = -1.0e9f;
      }
      float mx[8];
      #pragma unroll
      for (int i = 0; i < 8; i++) mx[i] = fmaxf(p[2 * i], p[2 * i + 1]);
      #pragma unroll
      for (int i = 0; i < 4; i++) mx[i] = fmaxf(mx[i], mx[i + 4]);
      mx[0] = fmaxf(mx[0], mx[2]); mx[1] = fmaxf(mx[1], mx[3]);
      float pmax = fmaxf(mx[0], mx[1]);
      pmax = fmaxf(pmax, __shfl_xor(pmax, 32, 64));
      if (__any(pmax > mrow + 8.0f)) {
        float mn = fmaxf(mrow, pmax);
        float sf = __expf(mrow - mn);
        lrow *= sf; mrow = mn;
        #pragma unroll
        for (int vc = 0; vc < 4; vc++)
          #pragma unroll
          for (int r = 0; r < 16; r++) O[vc][r] *= sf;
      }
      #pragma unroll
      for (int r = 0; r < 16; r++) p[r] = __expf(p[r] - mrow);
      float sm[8];
      #pragma unroll
      for (int i = 0; i < 8; i++) sm[i] = p[2 * i] + p[2 * i + 1];
      #pragma unroll
      for (int i = 0; i < 4; i++) sm[i] += sm[i + 4];
      float psum = (sm[0] + sm[1]) + (sm[2] + sm[3]);
      psum += __shfl_xor(psum, 32, 64);
      lrow += psum;
      unsigned int pk[2][4], sw[2][4];
      #pragma unroll
      for (int c = 0; c < 2; c++)
        #pragma unroll
        for (int k = 0; k < 4; k++) {
          unsigned int r_;
          asm("v_cvt_pk_bf16_f32 %0, %1, %2" : "=v"(r_)
              : "v"(p[8 * c + 2 * k]), "v"(p[8 * c + 2 * k + 1]));
          pk[c][k] = r_;
          sw[c][k] = (unsigned int)__shfl_xor((int)r_, 32, 64);
        }
      bf16x8 pb[2];
      #pragma unroll
      for (int c = 0; c < 2; c++) {
        union { unsigned int u4[4]; bf16x8 v; } bw;
        bw.u4[0] = hi ? sw[c][2] : pk[c][0];
        bw.u4[1] = hi ? sw[c][3] : pk[c][1];
        bw.u4[2] = hi ? pk[c][2] : sw[c][0];
        bw.u4[3] = hi ? pk[c][3] : sw[c][1];
        pb[c] = bw.v;
      }
      #pragma unroll
      for (int vc = 0; vc < 4; vc++) {
        const char* vrow = vb + (vc * 32 + qcol) * 80 + hi * 16;
        bf16x8 va0 = *reinterpret_cast<const bf16x8*>(vrow);
        bf16x8 va1 = *reinterpret_cast<const bf16x8*>(vrow + 32);
        O[vc] = __builtin_amdgcn_mfma_f32_32x32x16_bf16(va0, pb[0], O[vc], 0, 0, 0);
        O[vc] = __builtin_amdgcn_mfma_f32_32x32x16_bf16(va1, pb[1], O[vc], 0, 0, 0);
      }
    }
    if (t + 1 < tend) {
      wr_lds(cur ^ 1);
      if (t + 2 < tend) ld_regs(t + 2);
    }
    asm volatile("s_waitcnt lgkmcnt(0)" ::: "memory");
    __builtin_amdgcn_s_barrier();
    cur ^= 1;
  }

  __syncthreads();                          // everyone done with K/V buffers
  float inv = lrow > 0.0f ? 1.0f / lrow : 0.0f;
  #pragma unroll
  for (int vc = 0; vc < 4; vc++)
    #pragma unroll
    for (int g = 0; g < 4; g++) {
      int v0 = vc * 32 + 8 * g + 4 * hi;
      ushort4 ov;
      ov.x = f2bf(O[vc][4 * g + 0] * inv); ov.y = f2bf(O[vc][4 * g + 1] * inv);
      ov.z = f2bf(O[vc][4 * g + 2] * inv); ov.w = f2bf(O[vc][4 * g + 3] * inv);
      *reinterpret_cast<ushort4*>(lds + (w * 32 + qcol) * 272 + v0 * 2) = ov;
    }
  __syncthreads();
  #pragma unroll
  for (int j = 0; j < 8; j++) {             // each instr: wave covers 1KB contiguous
    int row = w * 32 + j * 4 + (l >> 4);
    uint4 vv = *reinterpret_cast<const uint4*>(lds + row * 272 + (l & 15) * 16);
    *reinterpret_cast<uint4*>(opart + ((size_t)b * 128 + row) * DHEAD + (l & 15) * 8) = vv;
  }
  if (l < 32)
    mlbuf[(size_t)b * 128 + w * 32 + l] = make_float2(mrow, lrow);
}

// ---------- combine up to 7 chunk partials per (h, q-row) ----------
__global__ void k_comb2(const unsigned short* __restrict__ opart,
                        const float2* __restrict__ mlbuf,
                        unsigned short* __restrict__ z) {
  int g = blockIdx.x * 256 + threadIdx.x;     // 16h * 2048q * 16vg
  int vg = g & 15, q = (g >> 4) & 2047, h = g >> 15;
  int qt = q >> 7, r = q & 127;
  int base = 0;
  for (int j = 0; j < qt; j++) base += chunks_of(j);
  const int nc = chunks_of(qt);               // 1..7
  float m = -3.0e38f;
  float2 ml[7];
  #pragma unroll
  for (int cc = 0; cc < 7; cc++)
    if (cc < nc) {
      ml[cc] = mlbuf[(size_t)((base + cc) * 16 + h) * 128 + r];
      m = fmaxf(m, ml[cc].x);
    }
  float wts[7], wsum = 0.0f;
  #pragma unroll
  for (int cc = 0; cc < 7; cc++)
    if (cc < nc) {
      float wv = ml[cc].y > 0.0f ? ml[cc].y * __expf(ml[cc].x - m) : 0.0f;
      wts[cc] = wv; wsum += wv;
    }
  float wi = 1.0f / wsum;
  float acc[8] = {};
  #pragma unroll
  for (int cc = 0; cc < 7; cc++)
    if (cc < nc && wts[cc] > 0.0f) {
      float wv = wts[cc] * wi;
      bf16x8 v = *reinterpret_cast<const bf16x8*>(
          opart + ((size_t)((base + cc) * 16 + h) * 128 + r) * DHEAD + vg * 8);
      #pragma unroll
      for (int j = 0; j < 8; j++) acc[j] += wv * (float)v[j];
    }
  unsigned short* zp = z + (size_t)q * D_MODEL + h * DHEAD + vg * 8;
  ushort4 lo, hi4;
  lo.x = f2bf(acc[0]); lo.y = f2bf(acc[1]); lo.z = f2bf(acc[2]); lo.w = f2bf(acc[3]);
  hi4.x = f2bf(acc[4]); hi4.y = f2bf(acc[5]); hi4.z = f2bf(acc[6]); hi4.w = f2bf(acc[7]);
  *reinterpret_cast<ushort4*>(zp) = lo;
  *reinterpret_cast<ushort4*>(zp + 4) = hi4;
}

// ---------- output GEMM: out(S,D) = z @ obT^T; BM=64 BN=128 BK=64, grid 512 ----------
__global__ __launch_bounds__(256) void k_out2(
    const unsigned short* __restrict__ zb, const unsigned short* __restrict__ obT,
    float* __restrict__ out) {
  __shared__ char lds[49152];               // buf p @ p*24576: A[64][128B] | B[128][128B] @+8K
  const int tid = threadIdx.x, l = tid & 63, w = tid >> 6;
  const int lr = l & 15, lk = l >> 4;
  const int orig = blockIdx.x;
  const int wg = (orig & 7) * 64 + (orig >> 3);   // 512%8==0, bijective
  const int bx = wg & 31, by = wg >> 5;     // s-tile(64), n-tile(128)
  const int s0 = bx * 64, n0 = by * 128;
  const int wm = w >> 1, wn = w & 1;        // wave = 32 rows x 64 cols
  f32x4 acc[2][4] = {};

  auto stage = [&](int t, int buf) {        // 6 gl_lds/thread (2 A + 4 B)
    const int kt = t * 64;
    char* dst = lds + buf * 24576;
    #pragma unroll
    for (int j = 0; j < 2; j++) {           // A: 64 rows x 8 chunks = 512
      int ci = tid + j * 256;
      int r = ci >> 3, c8 = ci & 7;
      int csrc = (c8 ^ (r & 7)) * 8;
      gl_lds16(zb + (size_t)(s0 + r) * D_MODEL + kt + csrc, dst + ci * 16);
    }
    #pragma unroll
    for (int j = 0; j < 4; j++) {           // B: 128 rows x 8 chunks = 1024
      int ci = tid + j * 256;
      int r = ci >> 3, c8 = ci & 7;
      int csrc = (c8 ^ (r & 7)) * 8;
      gl_lds16(obT + (size_t)(n0 + r) * D_MODEL + kt + csrc, dst + 8192 + ci * 16);
    }
  };

  stage(0, 0);
  int cur = 0;
  const int nT = D_MODEL / 64;
  for (int t = 0; t < nT; t++) {
    if (t + 1 < nT) {
      stage(t + 1, cur ^ 1);
      asm volatile("s_waitcnt vmcnt(6)" ::: "memory");
    } else {
      asm volatile("s_waitcnt vmcnt(0)" ::: "memory");
    }
    __builtin_amdgcn_s_barrier();
    const char* base = lds + cur * 24576;
    #pragma unroll
    for (int kk = 0; kk < 2; kk++) {
      const int kb = kk * 64 + lk * 16;
      bf16x8 a[2], b[4];
      #pragma unroll
      for (int mf = 0; mf < 2; mf++) {
        int rr = wm * 32 + mf * 16 + lr;
        a[mf] = *reinterpret_cast<const bf16x8*>(base + rr * 128 + (kb ^ ((rr & 7) << 4)));
      }
      #pragma unroll
      for (int nf = 0; nf < 4; nf++) {
        int rn = wn * 64 + nf * 16 + lr;
        b[nf] = *reinterpret_cast<const bf16x8*>(base + 8192 + rn * 128 + (kb ^ ((rn & 7) << 4)));
      }
      #pragma unroll
      for (int mf = 0; mf < 2; mf++)
        #pragma unroll
        for (int nf = 0; nf < 4; nf++)
          acc[mf][nf] = __builtin_amdgcn_mfma_f32_16x16x32_bf16(a[mf], b[nf], acc[mf][nf], 0, 0, 0);
    }
    asm volatile("s_waitcnt lgkmcnt(0)" ::: "memory");
    __builtin_amdgcn_s_barrier();
    cur ^= 1;
  }
  const float osc = 0.022097086912079608f;      // 1/sqrt(2048)
  #pragma unroll
  for (int mf = 0; mf < 2; mf++)
    #pragma unroll
    for (int nf = 0; nf < 4; nf++)
      #pragma unroll
      for (int rg = 0; rg < 4; rg++)
        out[(size_t)(s0 + wm * 32 + mf * 16 + lk * 4 + rg) * D_MODEL + n0 + wn * 64 + nf * 16 + lr]
            = acc[mf][nf][rg] * osc;
}

extern "C" void kernel_launch(void* const* d_in, const int* in_sizes, int n_in,
                              void* d_out, int out_size, void* d_ws, size_t ws_size,
                              hipStream_t stream) {
  const float* x = (const float*)d_in[0];
  const float* q = (const float*)d_in[1];
  const float* k = (const float*)d_in[2];
  const float* v = (const float*)d_in[3];
  const float* o = (const float*)d_in[4];
  const float* theta = (const float*)d_in[5];
  float* out = (float*)d_out;

  char* ws = (char*)d_ws;
  const size_t MB = 1u << 20;
  unsigned short* xb  = (unsigned short*)(ws + 0 * MB);
  unsigned short* qbT = (unsigned short*)(ws + 8 * MB);   // merged W^T[6144][2048] start
  unsigned short* obT = (unsigned short*)(ws + 32 * MB);
  unsigned short* rq  = (unsigned short*)(ws + 40 * MB);
  unsigned short* rk  = (unsigned short*)(ws + 48 * MB);
  unsigned short* vst = (unsigned short*)(ws + 56 * MB);
  float* sint = (float*)(ws + 64 * MB);
  float* cost = (float*)(ws + 64 * MB + 512 * 1024);
  unsigned short* opart = (unsigned short*)(ws + 0 * MB);   // 976*128*128*2B = 30.5MB
  float2* mlbuf         = (float2*)(ws + 31 * MB);          // 976*128*8B ~ 1MB
  unsigned short* zb    = (unsigned short*)(ws + 40 * MB);  // reuse rq (dead after attn)

  k_prep<<<dim3(20992), dim3(256), 0, stream>>>(x, q, k, v, o, theta, xb, qbT, obT, sint, cost);
  k_proj2<<<dim3(768), dim3(256), 0, stream>>>(xb, qbT, sint, cost, rq, rk, vst);
  k_attn6<<<dim3(976), dim3(256), 0, stream>>>(rq, rk, vst, opart, mlbuf);
  k_comb2<<<dim3(2048), dim3(256), 0, stream>>>(opart, mlbuf, zb);
  k_out2<<<dim3(512), dim3(256), 0, stream>>>(zb, obT, out);
}